// Round 1
// baseline (216.993 us; speedup 1.0000x reference)
//
#include <hip/hip_runtime.h>
#include <hip/hip_bf16.h>
#include <hip/hip_fp16.h>

typedef _Float16 half8 __attribute__((ext_vector_type(8)));
typedef _Float16 half4v __attribute__((ext_vector_type(4)));
typedef float float4v __attribute__((ext_vector_type(4)));

#define MFMA_F16(a, b, c) __builtin_amdgcn_mfma_f32_16x16x32_f16((a), (b), (c), 0, 0, 0)

// Problem constants
#define BATCH 8
#define SEQ   2048
#define DIM   1024
#define QD    128

// ---------------------------------------------------------------------------
// Projection: C(16384x128) = X(16384x1024) * W(128x1024)^T for W in {Wq,Wk,Wv}
// fp32 inputs -> fp16 outputs. v is stored transposed: vt[b][d][t].
// ---------------------------------------------------------------------------
__global__ __launch_bounds__(256) void proj_kernel(
    const float* __restrict__ x,
    const float* __restrict__ Wq,
    const float* __restrict__ Wk,
    const float* __restrict__ Wv,
    _Float16* __restrict__ q_out,   // (B*T, 128)
    _Float16* __restrict__ k_out,   // (B*T, 128)
    _Float16* __restrict__ vt_out)  // (B, 128, T)
{
    const int LDA = 40;  // 32 + 8 pad (fp16 elems); keeps 16B alignment, 2-way-only bank aliasing
    __shared__ _Float16 As[128 * 40];
    __shared__ _Float16 Bs[128 * 40];

    const int tid  = threadIdx.x;
    const int lane = tid & 63;
    const int wave = tid >> 6;
    const int quad = lane >> 4;
    const int l15  = lane & 15;
    const int wm   = (wave >> 1) * 64;   // wave row offset in 128x128 tile
    const int wn   = (wave & 1) * 64;    // wave col offset

    const int mblk  = blockIdx.x;        // 0..127
    const int which = blockIdx.y;        // 0=q 1=k 2=v
    const float* W = (which == 0) ? Wq : ((which == 1) ? Wk : Wv);

    const int row0 = mblk * 128;

    float4v acc[4][4];
#pragma unroll
    for (int i = 0; i < 4; i++)
#pragma unroll
        for (int j = 0; j < 4; j++)
            acc[i][j] = (float4v){0.f, 0.f, 0.f, 0.f};

    for (int kk = 0; kk < DIM; kk += 32) {
        __syncthreads();
        // Stage A (x) and B (W) tiles: 128 rows x 32 cols fp32 -> fp16 LDS.
        // 1024 float4 chunks each, 256 threads -> 4 chunks/thread, coalesced.
#pragma unroll
        for (int c = 0; c < 4; c++) {
            int chunk = c * 256 + tid;
            int r  = chunk >> 3;          // 0..127
            int cc = (chunk & 7) * 4;     // 0..28
            float4 fa = *(const float4*)(x + (size_t)(row0 + r) * DIM + kk + cc);
            _Float16* da = &As[r * LDA + cc];
            da[0] = (_Float16)fa.x; da[1] = (_Float16)fa.y;
            da[2] = (_Float16)fa.z; da[3] = (_Float16)fa.w;
            float4 fb = *(const float4*)(W + (size_t)r * DIM + kk + cc);
            _Float16* db = &Bs[r * LDA + cc];
            db[0] = (_Float16)fb.x; db[1] = (_Float16)fb.y;
            db[2] = (_Float16)fb.z; db[3] = (_Float16)fb.w;
        }
        __syncthreads();

        half8 af[4], bf[4];
#pragma unroll
        for (int i = 0; i < 4; i++)
            af[i] = *(const half8*)&As[(wm + i * 16 + l15) * LDA + quad * 8];
#pragma unroll
        for (int j = 0; j < 4; j++)
            bf[j] = *(const half8*)&Bs[(wn + j * 16 + l15) * LDA + quad * 8];
#pragma unroll
        for (int i = 0; i < 4; i++)
#pragma unroll
            for (int j = 0; j < 4; j++)
                acc[i][j] = MFMA_F16(af[i], bf[j], acc[i][j]);
    }

    // Epilogue. C layout (16x16): col = lane&15, row = quad*4 + reg.
    if (which == 2) {
        // store transposed: vt[b][col][t], pack 4 consecutive t as one 8B store
#pragma unroll
        for (int i = 0; i < 4; i++) {
            int grow0 = row0 + wm + i * 16 + quad * 4;   // global row of reg 0
            int b  = grow0 >> 11;
            int t0 = grow0 & 2047;
#pragma unroll
            for (int j = 0; j < 4; j++) {
                int col = wn + j * 16 + l15;
                half4v h;
#pragma unroll
                for (int r = 0; r < 4; r++) h[r] = (_Float16)acc[i][j][r];
                *(half4v*)&vt_out[((size_t)(b * QD + col)) * SEQ + t0] = h;
            }
        }
    } else {
        _Float16* out = (which == 0) ? q_out : k_out;
#pragma unroll
        for (int i = 0; i < 4; i++) {
            int grow0 = row0 + wm + i * 16 + quad * 4;
#pragma unroll
            for (int j = 0; j < 4; j++) {
                int col = wn + j * 16 + l15;
#pragma unroll
                for (int r = 0; r < 4; r++)
                    out[(size_t)(grow0 + r) * QD + col] = (_Float16)acc[i][j][r];
            }
        }
    }
}

// ---------------------------------------------------------------------------
// Flash attention: per (batch, 64-row q-tile). 4 waves, each owns 16 q rows.
// Online softmax over 32 key blocks of 64.
// ---------------------------------------------------------------------------
__global__ __launch_bounds__(256) void attn_kernel(
    const _Float16* __restrict__ q,    // (B*T, 128)
    const _Float16* __restrict__ k,    // (B*T, 128)
    const _Float16* __restrict__ vt,   // (B, 128, T)
    const int* __restrict__ mask,      // (B*T) 0/1
    float* __restrict__ out)           // (B*T, 128) fp32
{
    const int LDK = 136;  // 128 + 8 pad
    const int LDV = 72;   // 64 + 8 pad
    const int LDP = 72;
    __shared__ _Float16 Ks[64 * 136];
    __shared__ _Float16 Vs[128 * 72];
    __shared__ _Float16 Ps[4 * 16 * 72];
    __shared__ int Ms[64];

    const int tid  = threadIdx.x;
    const int lane = tid & 63;
    const int wave = tid >> 6;
    const int quad = lane >> 4;
    const int l15  = lane & 15;

    const int b  = blockIdx.y;
    const int tb = blockIdx.x * 64;

    // Q fragments, A-layout: m = lane&15 (row), k = quad*8 + j. Resident in regs.
    half8 qf[4];
    {
        const _Float16* qrow = q + ((size_t)(b * SEQ + tb + wave * 16 + l15)) * QD + quad * 8;
#pragma unroll
        for (int kc = 0; kc < 4; kc++)
            qf[kc] = *(const half8*)(qrow + kc * 32);
    }

    float4v oacc[8];
#pragma unroll
    for (int n = 0; n < 8; n++) oacc[n] = (float4v){0.f, 0.f, 0.f, 0.f};
    float mrow[4] = {-1e30f, -1e30f, -1e30f, -1e30f};
    float lrow[4] = {0.f, 0.f, 0.f, 0.f};

    _Float16* Pw = &Ps[wave * 16 * LDP];

    for (int sb = 0; sb < SEQ; sb += 64) {
        __syncthreads();
        // Stage K block: 64 keys x 128 d (row-major), 16B chunks
#pragma unroll
        for (int c = 0; c < 4; c++) {
            int chunk = c * 256 + tid;
            int r  = chunk >> 4;          // key 0..63
            int cc = (chunk & 15) * 8;    // d offset
            *(half8*)&Ks[r * LDK + cc] =
                *(const half8*)(k + ((size_t)(b * SEQ + sb + r)) * QD + cc);
        }
        // Stage V^T block: 128 d x 64 keys
#pragma unroll
        for (int c = 0; c < 4; c++) {
            int chunk = c * 256 + tid;
            int r  = chunk >> 3;          // d 0..127
            int cc = (chunk & 7) * 8;     // key offset
            *(half8*)&Vs[r * LDV + cc] =
                *(const half8*)(vt + ((size_t)(b * QD + r)) * SEQ + sb + cc);
        }
        if (tid < 64) Ms[tid] = mask[b * SEQ + sb + tid];
        __syncthreads();

        // S = Q K^T  (16 rows x 64 keys per wave), C layout
        float4v sacc[4];
#pragma unroll
        for (int j = 0; j < 4; j++) {
            float4v a = (float4v){0.f, 0.f, 0.f, 0.f};
#pragma unroll
            for (int kc = 0; kc < 4; kc++) {
                half8 kf = *(const half8*)&Ks[(j * 16 + l15) * LDK + kc * 32 + quad * 8];
                a = MFMA_F16(qf[kc], kf, a);
            }
            sacc[j] = a;
        }

        // Mask + row max
        float rmax[4] = {-1e30f, -1e30f, -1e30f, -1e30f};
#pragma unroll
        for (int j = 0; j < 4; j++) {
            bool mk = (Ms[j * 16 + l15] != 0);
#pragma unroll
            for (int r = 0; r < 4; r++) {
                float s = mk ? sacc[j][r] : -1e30f;
                sacc[j][r] = s;
                rmax[r] = fmaxf(rmax[r], s);
            }
        }
#pragma unroll
        for (int d = 1; d < 16; d <<= 1)
#pragma unroll
            for (int r = 0; r < 4; r++)
                rmax[r] = fmaxf(rmax[r], __shfl_xor(rmax[r], d, 64));

        // Online softmax update
        float alpha[4];
#pragma unroll
        for (int r = 0; r < 4; r++) {
            float mnew = fmaxf(mrow[r], rmax[r]);
            alpha[r] = __expf(mrow[r] - mnew);
            mrow[r] = mnew;
        }
        float p[4][4];
#pragma unroll
        for (int j = 0; j < 4; j++)
#pragma unroll
            for (int r = 0; r < 4; r++)
                p[j][r] = (sacc[j][r] > -1e29f) ? __expf(sacc[j][r] - mrow[r]) : 0.f;
#pragma unroll
        for (int r = 0; r < 4; r++) {
            float s = p[0][r] + p[1][r] + p[2][r] + p[3][r];
#pragma unroll
            for (int d = 1; d < 16; d <<= 1) s += __shfl_xor(s, d, 64);
            lrow[r] = lrow[r] * alpha[r] + s;
        }
#pragma unroll
        for (int n = 0; n < 8; n++)
#pragma unroll
            for (int r = 0; r < 4; r++)
                oacc[n][r] *= alpha[r];

        // P: C-layout -> LDS -> A-layout (wave-private region, no barrier needed)
#pragma unroll
        for (int j = 0; j < 4; j++) {
            int col = j * 16 + l15;
#pragma unroll
            for (int r = 0; r < 4; r++)
                Pw[(quad * 4 + r) * LDP + col] = (_Float16)p[j][r];
        }

        // O += P V  (K = 64 keys, 2 chunks of 32)
#pragma unroll
        for (int kc = 0; kc < 2; kc++) {
            half8 pf = *(const half8*)&Pw[l15 * LDP + kc * 32 + quad * 8];
#pragma unroll
            for (int n = 0; n < 8; n++) {
                half8 vf = *(const half8*)&Vs[(n * 16 + l15) * LDV + kc * 32 + quad * 8];
                oacc[n] = MFMA_F16(pf, vf, oacc[n]);
            }
        }
    }

    // Epilogue: divide by l, write fp32
    float inv_l[4];
#pragma unroll
    for (int r = 0; r < 4; r++)
        inv_l[r] = (lrow[r] > 0.f) ? (1.0f / lrow[r]) : 0.f;
#pragma unroll
    for (int n = 0; n < 8; n++) {
        int col = n * 16 + l15;
#pragma unroll
        for (int r = 0; r < 4; r++) {
            int row = tb + wave * 16 + quad * 4 + r;
            out[((size_t)(b * SEQ + row)) * QD + col] = oacc[n][r] * inv_l[r];
        }
    }
}

extern "C" void kernel_launch(void* const* d_in, const int* in_sizes, int n_in,
                              void* d_out, int out_size, void* d_ws, size_t ws_size,
                              hipStream_t stream) {
    const float* x    = (const float*)d_in[0];
    const int*   mask = (const int*)d_in[1];
    const float* Wq   = (const float*)d_in[2];
    const float* Wk   = (const float*)d_in[3];
    const float* Wv   = (const float*)d_in[4];
    float* out = (float*)d_out;

    _Float16* qb  = (_Float16*)d_ws;                       // 16384*128 fp16 = 4MB
    _Float16* kb  = qb + (size_t)BATCH * SEQ * QD;         // 4MB
    _Float16* vtb = kb + (size_t)BATCH * SEQ * QD;         // 4MB (transposed)

    proj_kernel<<<dim3(128, 3), 256, 0, stream>>>(x, Wq, Wk, Wv, qb, kb, vtb);
    attn_kernel<<<dim3(SEQ / 64, BATCH), 256, 0, stream>>>(qb, kb, vtb, mask, out);
}

// Round 2
// 210.906 us; speedup vs baseline: 1.0289x; 1.0289x over previous
//
#include <hip/hip_runtime.h>
#include <hip/hip_bf16.h>
#include <hip/hip_fp16.h>

typedef _Float16 half8 __attribute__((ext_vector_type(8)));
typedef _Float16 half4v __attribute__((ext_vector_type(4)));
typedef float float4v __attribute__((ext_vector_type(4)));

#define MFMA_F16(a, b, c) __builtin_amdgcn_mfma_f32_16x16x32_f16((a), (b), (c), 0, 0, 0)

// Problem constants
#define BATCH 8
#define SEQ   2048
#define DIM   1024
#define QD    128
#define BT    (BATCH * SEQ)          // 16384

// ---------------------------------------------------------------------------
// fp32 -> fp16 converts (BW-bound)
// ---------------------------------------------------------------------------
__global__ __launch_bounds__(256) void cvt_x_kernel(const float* __restrict__ s,
                                                    _Float16* __restrict__ d) {
    int i = blockIdx.x * 256 + threadIdx.x;   // one float4 each; grid sized exactly
    float4 f = ((const float4*)s)[i];
    half4v h = {(_Float16)f.x, (_Float16)f.y, (_Float16)f.z, (_Float16)f.w};
    ((half4v*)d)[i] = h;
}

__global__ __launch_bounds__(256) void cvt_w_kernel(const float* __restrict__ Wq,
                                                    const float* __restrict__ Wk,
                                                    const float* __restrict__ Wv,
                                                    _Float16* __restrict__ Wh) {
    const float* src = (blockIdx.y == 0) ? Wq : ((blockIdx.y == 1) ? Wk : Wv);
    int i = blockIdx.x * 256 + threadIdx.x;   // 32768 float4 per W
    float4 f = ((const float4*)src)[i];
    half4v h = {(_Float16)f.x, (_Float16)f.y, (_Float16)f.z, (_Float16)f.w};
    ((half4v*)(Wh + (size_t)blockIdx.y * QD * DIM))[i] = h;
}

// ---------------------------------------------------------------------------
// Projection from pre-converted fp16: C(16384x128) = Xh * Wh^T.
// v stored transposed: vt[b][d][t].
// ---------------------------------------------------------------------------
__global__ __launch_bounds__(256) void proj_f16_kernel(
    const _Float16* __restrict__ xh,
    const _Float16* __restrict__ Wh,     // 3 concatenated (128x1024) matrices
    _Float16* __restrict__ q_out,
    _Float16* __restrict__ k_out,
    _Float16* __restrict__ vt_out)
{
    const int LDA = 40;  // 32 + 8 pad halfs: row stride 20 dwords -> ~2-way only
    __shared__ _Float16 As[128 * 40];
    __shared__ _Float16 Bs[128 * 40];

    const int tid  = threadIdx.x;
    const int lane = tid & 63;
    const int wave = tid >> 6;
    const int quad = lane >> 4;
    const int l15  = lane & 15;
    const int wm   = (wave >> 1) * 64;
    const int wn   = (wave & 1) * 64;

    const int mblk  = blockIdx.x;        // 0..127
    const int which = blockIdx.y;        // 0=q 1=k 2=v
    const _Float16* W = Wh + (size_t)which * QD * DIM;
    const int row0 = mblk * 128;

    float4v acc[4][4];
#pragma unroll
    for (int i = 0; i < 4; i++)
#pragma unroll
        for (int j = 0; j < 4; j++)
            acc[i][j] = (float4v){0.f, 0.f, 0.f, 0.f};

    for (int kk = 0; kk < DIM; kk += 32) {
        __syncthreads();
        // As: 128x32 halfs (512 16B-chunks), Bs: same. 4 chunks/thread total.
#pragma unroll
        for (int c = 0; c < 2; c++) {
            int chunk = c * 256 + tid;        // 0..511
            int r  = chunk >> 2;
            int cc = (chunk & 3) * 8;
            *(half8*)&As[r * LDA + cc] =
                *(const half8*)(xh + (size_t)(row0 + r) * DIM + kk + cc);
            *(half8*)&Bs[r * LDA + cc] =
                *(const half8*)(W + (size_t)r * DIM + kk + cc);
        }
        __syncthreads();

        half8 af[4], bf[4];
#pragma unroll
        for (int i = 0; i < 4; i++)
            af[i] = *(const half8*)&As[(wm + i * 16 + l15) * LDA + quad * 8];
#pragma unroll
        for (int j = 0; j < 4; j++)
            bf[j] = *(const half8*)&Bs[(wn + j * 16 + l15) * LDA + quad * 8];
#pragma unroll
        for (int i = 0; i < 4; i++)
#pragma unroll
            for (int j = 0; j < 4; j++)
                acc[i][j] = MFMA_F16(af[i], bf[j], acc[i][j]);
    }

    if (which == 2) {
#pragma unroll
        for (int i = 0; i < 4; i++) {
            int grow0 = row0 + wm + i * 16 + quad * 4;
            int b  = grow0 >> 11;
            int t0 = grow0 & 2047;
#pragma unroll
            for (int j = 0; j < 4; j++) {
                int col = wn + j * 16 + l15;
                half4v h;
#pragma unroll
                for (int r = 0; r < 4; r++) h[r] = (_Float16)acc[i][j][r];
                *(half4v*)&vt_out[((size_t)(b * QD + col)) * SEQ + t0] = h;
            }
        }
    } else {
        _Float16* out = (which == 0) ? q_out : k_out;
#pragma unroll
        for (int i = 0; i < 4; i++) {
            int grow0 = row0 + wm + i * 16 + quad * 4;
#pragma unroll
            for (int j = 0; j < 4; j++) {
                int col = wn + j * 16 + l15;
#pragma unroll
                for (int r = 0; r < 4; r++)
                    out[(size_t)(grow0 + r) * QD + col] = (_Float16)acc[i][j][r];
            }
        }
    }
}

// ---------------------------------------------------------------------------
// Projection from fp32 (fallback when ws too small for xh): round-1 kernel.
// ---------------------------------------------------------------------------
__global__ __launch_bounds__(256) void proj_f32_kernel(
    const float* __restrict__ x,
    const float* __restrict__ Wq,
    const float* __restrict__ Wk,
    const float* __restrict__ Wv,
    _Float16* __restrict__ q_out,
    _Float16* __restrict__ k_out,
    _Float16* __restrict__ vt_out)
{
    const int LDA = 40;
    __shared__ _Float16 As[128 * 40];
    __shared__ _Float16 Bs[128 * 40];

    const int tid  = threadIdx.x;
    const int lane = tid & 63;
    const int wave = tid >> 6;
    const int quad = lane >> 4;
    const int l15  = lane & 15;
    const int wm   = (wave >> 1) * 64;
    const int wn   = (wave & 1) * 64;

    const int mblk  = blockIdx.x;
    const int which = blockIdx.y;
    const float* W = (which == 0) ? Wq : ((which == 1) ? Wk : Wv);
    const int row0 = mblk * 128;

    float4v acc[4][4];
#pragma unroll
    for (int i = 0; i < 4; i++)
#pragma unroll
        for (int j = 0; j < 4; j++)
            acc[i][j] = (float4v){0.f, 0.f, 0.f, 0.f};

    for (int kk = 0; kk < DIM; kk += 32) {
        __syncthreads();
#pragma unroll
        for (int c = 0; c < 4; c++) {
            int chunk = c * 256 + tid;
            int r  = chunk >> 3;
            int cc = (chunk & 7) * 4;
            float4 fa = *(const float4*)(x + (size_t)(row0 + r) * DIM + kk + cc);
            _Float16* da = &As[r * LDA + cc];
            da[0] = (_Float16)fa.x; da[1] = (_Float16)fa.y;
            da[2] = (_Float16)fa.z; da[3] = (_Float16)fa.w;
            float4 fb = *(const float4*)(W + (size_t)r * DIM + kk + cc);
            _Float16* db = &Bs[r * LDA + cc];
            db[0] = (_Float16)fb.x; db[1] = (_Float16)fb.y;
            db[2] = (_Float16)fb.z; db[3] = (_Float16)fb.w;
        }
        __syncthreads();

        half8 af[4], bf[4];
#pragma unroll
        for (int i = 0; i < 4; i++)
            af[i] = *(const half8*)&As[(wm + i * 16 + l15) * LDA + quad * 8];
#pragma unroll
        for (int j = 0; j < 4; j++)
            bf[j] = *(const half8*)&Bs[(wn + j * 16 + l15) * LDA + quad * 8];
#pragma unroll
        for (int i = 0; i < 4; i++)
#pragma unroll
            for (int j = 0; j < 4; j++)
                acc[i][j] = MFMA_F16(af[i], bf[j], acc[i][j]);
    }

    if (which == 2) {
#pragma unroll
        for (int i = 0; i < 4; i++) {
            int grow0 = row0 + wm + i * 16 + quad * 4;
            int b  = grow0 >> 11;
            int t0 = grow0 & 2047;
#pragma unroll
            for (int j = 0; j < 4; j++) {
                int col = wn + j * 16 + l15;
                half4v h;
#pragma unroll
                for (int r = 0; r < 4; r++) h[r] = (_Float16)acc[i][j][r];
                *(half4v*)&vt_out[((size_t)(b * QD + col)) * SEQ + t0] = h;
            }
        }
    } else {
        _Float16* out = (which == 0) ? q_out : k_out;
#pragma unroll
        for (int i = 0; i < 4; i++) {
            int grow0 = row0 + wm + i * 16 + quad * 4;
#pragma unroll
            for (int j = 0; j < 4; j++) {
                int col = wn + j * 16 + l15;
#pragma unroll
                for (int r = 0; r < 4; r++)
                    out[(size_t)(grow0 + r) * QD + col] = (_Float16)acc[i][j][r];
            }
        }
    }
}

// ---------------------------------------------------------------------------
// Flash attention, key-split. Each block: 64 q rows x (SEQ/NSPLIT) keys.
// DIRECT=true (NSPLIT==1): writes normalized output. Otherwise writes
// unnormalized O-partial + (m,l) per row for the merge pass.
// Row-sum comes from an extra ones-column PV MFMA (no shuffle reduction).
// ---------------------------------------------------------------------------
template<int NSPLIT, bool DIRECT>
__global__ __launch_bounds__(256) void attn_kernel(
    const _Float16* __restrict__ q,    // (B*T, 128)
    const _Float16* __restrict__ k,    // (B*T, 128)
    const _Float16* __restrict__ vt,   // (B, 128, T)
    const int* __restrict__ mask,      // (B*T) 0/1
    float* __restrict__ out,           // DIRECT: (B*T,128); else O-partials (NSPLIT,B*T,128)
    float2* __restrict__ ml)           // (NSPLIT, B*T) — unused if DIRECT
{
    const int LDK = 136;  // 128 + 8 pad
    const int LDV = 72;   // 64 + 8 pad
    const int LDP = 72;
    __shared__ _Float16 Ks[64 * 136];
    __shared__ _Float16 Vs[128 * 72];
    __shared__ _Float16 Ps[4 * 16 * 72];
    __shared__ int Ms[64];

    const int tid  = threadIdx.x;
    const int lane = tid & 63;
    const int wave = tid >> 6;
    const int quad = lane >> 4;
    const int l15  = lane & 15;

    const int b  = blockIdx.y;
    const int tb = blockIdx.x * 64;
    const int z  = blockIdx.z;
    const int KSPAN = SEQ / NSPLIT;

    half8 qf[4];
    {
        const _Float16* qrow = q + ((size_t)(b * SEQ + tb + wave * 16 + l15)) * QD + quad * 8;
#pragma unroll
        for (int kc = 0; kc < 4; kc++)
            qf[kc] = *(const half8*)(qrow + kc * 32);
    }

    const half8 onesv = {(_Float16)1, (_Float16)1, (_Float16)1, (_Float16)1,
                         (_Float16)1, (_Float16)1, (_Float16)1, (_Float16)1};

    float4v oacc[8];
#pragma unroll
    for (int n = 0; n < 8; n++) oacc[n] = (float4v){0.f, 0.f, 0.f, 0.f};
    float4v lacc = (float4v){0.f, 0.f, 0.f, 0.f};
    float mrow[4] = {-1e30f, -1e30f, -1e30f, -1e30f};

    _Float16* Pw = &Ps[wave * 16 * LDP];

    for (int sb = z * KSPAN; sb < (z + 1) * KSPAN; sb += 64) {
        __syncthreads();
#pragma unroll
        for (int c = 0; c < 4; c++) {
            int chunk = c * 256 + tid;
            int r  = chunk >> 4;
            int cc = (chunk & 15) * 8;
            *(half8*)&Ks[r * LDK + cc] =
                *(const half8*)(k + ((size_t)(b * SEQ + sb + r)) * QD + cc);
        }
#pragma unroll
        for (int c = 0; c < 4; c++) {
            int chunk = c * 256 + tid;
            int r  = chunk >> 3;
            int cc = (chunk & 7) * 8;
            *(half8*)&Vs[r * LDV + cc] =
                *(const half8*)(vt + ((size_t)(b * QD + r)) * SEQ + sb + cc);
        }
        if (tid < 64) Ms[tid] = mask[b * SEQ + sb + tid];
        __syncthreads();

        // S = Q K^T (16 rows x 64 keys per wave), C layout
        float4v sacc[4];
#pragma unroll
        for (int j = 0; j < 4; j++) {
            float4v a = (float4v){0.f, 0.f, 0.f, 0.f};
#pragma unroll
            for (int kc = 0; kc < 4; kc++) {
                half8 kf = *(const half8*)&Ks[(j * 16 + l15) * LDK + kc * 32 + quad * 8];
                a = MFMA_F16(qf[kc], kf, a);
            }
            sacc[j] = a;
        }

        // Mask + row max (shuffle over the 16 lanes holding a row)
        float rmax[4] = {-1e30f, -1e30f, -1e30f, -1e30f};
#pragma unroll
        for (int j = 0; j < 4; j++) {
            bool mk = (Ms[j * 16 + l15] != 0);
#pragma unroll
            for (int r = 0; r < 4; r++) {
                float s = mk ? sacc[j][r] : -1e30f;
                sacc[j][r] = s;
                rmax[r] = fmaxf(rmax[r], s);
            }
        }
#pragma unroll
        for (int d = 1; d < 16; d <<= 1)
#pragma unroll
            for (int r = 0; r < 4; r++)
                rmax[r] = fmaxf(rmax[r], __shfl_xor(rmax[r], d, 64));

        float alpha[4];
#pragma unroll
        for (int r = 0; r < 4; r++) {
            float mnew = fmaxf(mrow[r], rmax[r]);
            alpha[r] = __expf(mrow[r] - mnew);
            mrow[r] = mnew;
        }
        float p[4][4];
#pragma unroll
        for (int j = 0; j < 4; j++)
#pragma unroll
            for (int r = 0; r < 4; r++)
                p[j][r] = (sacc[j][r] > -1e29f) ? __expf(sacc[j][r] - mrow[r]) : 0.f;

#pragma unroll
        for (int n = 0; n < 8; n++)
#pragma unroll
            for (int r = 0; r < 4; r++)
                oacc[n][r] *= alpha[r];
#pragma unroll
        for (int r = 0; r < 4; r++) lacc[r] *= alpha[r];

        // P: C-layout -> LDS -> A-layout (wave-private, no barrier)
#pragma unroll
        for (int j = 0; j < 4; j++) {
            int col = j * 16 + l15;
#pragma unroll
            for (int r = 0; r < 4; r++)
                Pw[(quad * 4 + r) * LDP + col] = (_Float16)p[j][r];
        }

        // O += P V ; l += P 1 (ones-column MFMA, replaces shuffle sum)
#pragma unroll
        for (int kc = 0; kc < 2; kc++) {
            half8 pf = *(const half8*)&Pw[l15 * LDP + kc * 32 + quad * 8];
#pragma unroll
            for (int n = 0; n < 8; n++) {
                half8 vf = *(const half8*)&Vs[(n * 16 + l15) * LDV + kc * 32 + quad * 8];
                oacc[n] = MFMA_F16(pf, vf, oacc[n]);
            }
            lacc = MFMA_F16(pf, onesv, lacc);
        }
    }

    if (DIRECT) {
        float inv_l[4];
#pragma unroll
        for (int r = 0; r < 4; r++)
            inv_l[r] = (lacc[r] > 0.f) ? (1.0f / lacc[r]) : 0.f;
#pragma unroll
        for (int n = 0; n < 8; n++) {
            int col = n * 16 + l15;
#pragma unroll
            for (int r = 0; r < 4; r++) {
                int row = tb + wave * 16 + quad * 4 + r;
                out[((size_t)(b * SEQ + row)) * QD + col] = oacc[n][r] * inv_l[r];
            }
        }
    } else {
        float* Op = out + (size_t)z * BT * QD;
#pragma unroll
        for (int n = 0; n < 8; n++) {
            int col = n * 16 + l15;
#pragma unroll
            for (int r = 0; r < 4; r++) {
                int row = tb + wave * 16 + quad * 4 + r;
                Op[((size_t)(b * SEQ + row)) * QD + col] = oacc[n][r];
            }
        }
        if (l15 == 0) {
#pragma unroll
            for (int r = 0; r < 4; r++) {
                int row = tb + wave * 16 + quad * 4 + r;
                ml[(size_t)z * BT + b * SEQ + row] = make_float2(mrow[r], lacc[r]);
            }
        }
    }
}

// ---------------------------------------------------------------------------
// Merge: combine NSPLIT partials per row. One float4 of columns per thread.
// ---------------------------------------------------------------------------
template<int NS>
__global__ __launch_bounds__(256) void merge_kernel(
    const float* __restrict__ Op,     // (NS, B*T, 128)
    const float2* __restrict__ ml,    // (NS, B*T)
    float* __restrict__ out)          // (B*T, 128)
{
    int gid = blockIdx.x * 256 + threadIdx.x;   // B*T*32 total
    int row = gid >> 5;
    int c4  = gid & 31;

    float2 a[NS];
    float m = -3.0e38f;
#pragma unroll
    for (int s = 0; s < NS; s++) { a[s] = ml[(size_t)s * BT + row]; m = fmaxf(m, a[s].x); }
    float sc[NS];
    float denom = 0.f;
#pragma unroll
    for (int s = 0; s < NS; s++) { sc[s] = __expf(a[s].x - m); denom += sc[s] * a[s].y; }
    float inv = (denom > 0.f) ? (1.0f / denom) : 0.f;

    float4 acc = make_float4(0.f, 0.f, 0.f, 0.f);
#pragma unroll
    for (int s = 0; s < NS; s++) {
        float4 o = ((const float4*)Op)[(size_t)s * (BT * QD / 4) + row * 32 + c4];
        acc.x += o.x * sc[s]; acc.y += o.y * sc[s];
        acc.z += o.z * sc[s]; acc.w += o.w * sc[s];
    }
    acc.x *= inv; acc.y *= inv; acc.z *= inv; acc.w *= inv;
    ((float4*)out)[row * 32 + c4] = acc;
}

extern "C" void kernel_launch(void* const* d_in, const int* in_sizes, int n_in,
                              void* d_out, int out_size, void* d_ws, size_t ws_size,
                              hipStream_t stream) {
    const float* x    = (const float*)d_in[0];
    const int*   mask = (const int*)d_in[1];
    const float* Wq   = (const float*)d_in[2];
    const float* Wk   = (const float*)d_in[3];
    const float* Wv   = (const float*)d_in[4];
    float* out = (float*)d_out;

    // Workspace layout sizes (bytes)
    const size_t QKV_B   = (size_t)BT * QD * 2;          // 4 MB each, fp16
    const size_t XH_B    = (size_t)BT * DIM * 2;         // 32 MB
    const size_t WH_B    = (size_t)3 * QD * DIM * 2;     // 768 KB
    const size_t OP1_B   = (size_t)BT * QD * 4;          // 8 MB per split
    const size_t ML1_B   = (size_t)BT * 8;               // 128 KB per split

    const size_t NEED_LOW   = 3 * QKV_B;                               // ~12 MB
    const size_t NEED_MID   = 3 * QKV_B + 2 * OP1_B + 2 * ML1_B;       // ~28 MB
    const size_t NEED_F2    = NEED_MID + XH_B + WH_B;                  // ~61 MB
    const size_t NEED_F4    = 3 * QKV_B + 4 * OP1_B + 4 * ML1_B + XH_B + WH_B; // ~78 MB

    char* p = (char*)d_ws;
    int nsplit;
    bool use_xh;
    if (ws_size >= NEED_F4)      { nsplit = 4; use_xh = true; }
    else if (ws_size >= NEED_F2) { nsplit = 2; use_xh = true; }
    else if (ws_size >= NEED_MID){ nsplit = 2; use_xh = false; }
    else                         { nsplit = 1; use_xh = false; (void)NEED_LOW; }

    _Float16 *xh = nullptr, *Wh = nullptr;
    if (use_xh) { xh = (_Float16*)p; p += XH_B; Wh = (_Float16*)p; p += WH_B; }
    _Float16* qb  = (_Float16*)p; p += QKV_B;
    _Float16* kb  = (_Float16*)p; p += QKV_B;
    _Float16* vtb = (_Float16*)p; p += QKV_B;
    float*  Op = (float*)p;  p += (size_t)nsplit * OP1_B;
    float2* ml = (float2*)p;

    if (use_xh) {
        cvt_x_kernel<<<dim3(BT * DIM / 4 / 256), 256, 0, stream>>>(x, xh);
        cvt_w_kernel<<<dim3(QD * DIM / 4 / 256, 3), 256, 0, stream>>>(Wq, Wk, Wv, Wh);
        proj_f16_kernel<<<dim3(BT / 128, 3), 256, 0, stream>>>(xh, Wh, qb, kb, vtb);
    } else {
        proj_f32_kernel<<<dim3(BT / 128, 3), 256, 0, stream>>>(x, Wq, Wk, Wv, qb, kb, vtb);
    }

    if (nsplit == 4) {
        attn_kernel<4, false><<<dim3(SEQ / 64, BATCH, 4), 256, 0, stream>>>(
            qb, kb, vtb, mask, Op, ml);
        merge_kernel<4><<<dim3(BT * 32 / 256), 256, 0, stream>>>(Op, ml, out);
    } else if (nsplit == 2) {
        attn_kernel<2, false><<<dim3(SEQ / 64, BATCH, 2), 256, 0, stream>>>(
            qb, kb, vtb, mask, Op, ml);
        merge_kernel<2><<<dim3(BT * 32 / 256), 256, 0, stream>>>(Op, ml, out);
    } else {
        attn_kernel<1, true><<<dim3(SEQ / 64, BATCH, 1), 256, 0, stream>>>(
            qb, kb, vtb, mask, out, nullptr);
    }
}